// Round 25
// baseline (327.081 us; speedup 1.0000x reference)
//
#include <hip/hip_runtime.h>
#include <stdint.h>

#define B_ 8
#define S_ 4096
#define D_ 192
#define M_ (B_*S_)

typedef short v8s __attribute__((ext_vector_type(8)));
typedef float v4f __attribute__((ext_vector_type(4)));
typedef unsigned short v4us __attribute__((ext_vector_type(4)));
typedef unsigned long long ull;

static __device__ __forceinline__ unsigned short f2bf(float f){
  union{float f; unsigned u;} v; v.f=f;
  unsigned u = v.u;
  unsigned r = (u + 0x7fffu + ((u>>16)&1u))>>16;
  return (unsigned short)r;
}
static __device__ __forceinline__ float bf2f(short s){
  union{unsigned u; float f;} v; v.u = ((unsigned)(unsigned short)s)<<16; return v.f;
}
static __device__ __forceinline__ float fexp2(float x){
  return __builtin_amdgcn_exp2f(x);
}
static __device__ __forceinline__ unsigned cvtpk(float lo, float hi){
  unsigned r;
  asm("v_cvt_pk_bf16_f32 %0, %1, %2" : "=v"(r) : "v"(lo), "v"(hi));
  return r;
}

// ---- fp8 e4m3fn pack ----
static __device__ __forceinline__ unsigned sw_fp8(float x){
  union{float f; unsigned u;} v; v.f = x;
  unsigned s = (v.u >> 24) & 0x80u;
  float a = fabsf(x);
  if (a < 0.001953125f) return s;
  if (a >= 240.f) return s | 0x7Eu;
  if (a < 0.015625f) {
    int m = (int)(a*512.f + 0.5f); if(m>7) m=7;
    return s | (unsigned)m;
  }
  int e = (int)((v.u >> 23) & 0xff) - 127;
  unsigned mant = (v.u >> 20) & 0x7u;
  unsigned rest = v.u & 0xFFFFFu;
  if (rest > 0x80000u || (rest == 0x80000u && (mant&1u))) mant++;
  unsigned ee = (unsigned)(e + 7);
  if (mant == 8u){ mant = 0u; ee++; }
  return s | (ee<<3) | mant;
}
template<bool HI>
static __device__ __forceinline__ unsigned pk8(float a, float b, unsigned old){
#if __has_builtin(__builtin_amdgcn_cvt_pk_fp8_f32)
  return __builtin_amdgcn_cvt_pk_fp8_f32(a, b, old, HI);
#else
  unsigned p = sw_fp8(a) | (sw_fp8(b)<<8);
  return HI ? ((old & 0x0000FFFFu) | (p<<16)) : ((old & 0xFFFF0000u) | p);
#endif
}

typedef const __attribute__((address_space(1))) unsigned int gu32;
typedef __attribute__((address_space(3))) unsigned int lu32;
#define GLL16(gp, lp) __builtin_amdgcn_global_load_lds((gu32*)(gp), (lu32*)(lp), 16, 0, 0)

// ---------------- weight conversion fp32 -> bf16 ----------------
__global__ void cvt_w_kernel(const float* w0,const float* w1,const float* w2,const float* w3,
                             const float* w4,const float* w5,const float* w6,const float* w7,
                             unsigned short* dst){
  int w = blockIdx.y;
  const float* src;
  switch(w){
    case 0: src=w0; break; case 1: src=w1; break; case 2: src=w2; break; case 3: src=w3; break;
    case 4: src=w4; break; case 5: src=w5; break; case 6: src=w6; break; default: src=w7; break;
  }
  int i = blockIdx.x*256 + threadIdx.x;
  float v = src[i];
  if(w==0 || w==4 || w==1 || w==5) v *= 0.32267249f;   // sqrt(log2(e)/sqrt(192))
  dst[(size_t)w*36864 + i] = f2bf(v);
}

// ---------------- fused QKV projection, split by path (round-24 form) -------
__global__ __launch_bounds__(256) void proj_kernel(
    const float* __restrict__ x, const unsigned short* __restrict__ Wb,
    unsigned char* __restrict__ QK8, unsigned short* __restrict__ V16)
{
  __shared__ __align__(16) unsigned short Vstage[192*72];   // 27.6 KB
  const size_t MDB = (size_t)M_*D_;
  const size_t MD  = (size_t)M_*D_;
  int path = blockIdx.y;
  int tid = threadIdx.x;
  int wid = tid>>6, lane = tid&63;
  int lr = lane&15, lg = lane>>4, kb = lg*8;
  int m0 = blockIdx.x*64 + wid*16;
  int row = m0 + lr;

  v8s a[6];
  #pragma unroll
  for(int c=0;c<6;c++){
    const float* xp = &x[(size_t)row*D_ + c*32 + kb];
    float4 f0 = *(const float4*)xp;
    float4 f1 = *(const float4*)(xp+4);
    v8s t;
    t[0]=(short)f2bf(f0.x); t[1]=(short)f2bf(f0.y); t[2]=(short)f2bf(f0.z); t[3]=(short)f2bf(f0.w);
    t[4]=(short)f2bf(f1.x); t[5]=(short)f2bf(f1.y); t[6]=(short)f2bf(f1.z); t[7]=(short)f2bf(f1.w);
    a[c]=t;
  }
  int bidx = m0 / S_;
  int sb   = (blockIdx.x*64) % S_;
  int sloc = wid*16 + lg*4;

  unsigned char* dstQ8 = QK8 + (size_t)path*2*MDB;
  for(int which=0; which<2; which++){
    const unsigned short* W = Wb + (size_t)(path*4 + which)*36864;
    unsigned char* dst = which==0 ? dstQ8 : dstQ8 + MDB;
    #pragma unroll
    for(int nt=0; nt<12; nt++){
      v4f acc = {0.f,0.f,0.f,0.f};
      int n = nt*16 + lr;
      #pragma unroll
      for(int c=0;c<6;c++){
        v8s bfr = *(const v8s*)&W[(size_t)n*D_ + c*32 + kb];
        acc = __builtin_amdgcn_mfma_f32_16x16x32_bf16(a[c], bfr, acc, 0,0,0);
      }
      int col = nt*16 + lr;
      int r0 = m0 + lg*4;
      #pragma unroll
      for(int r=0;r<4;r++){
        unsigned p = pk8<false>(acc[r], 0.f, 0u);
        dst[(size_t)(r0+r)*D_ + col] = (unsigned char)(p & 0xFF);
      }
    }
  }
  // V -> bf16 LDS transpose stage -> coalesced stores
  {
    const unsigned short* W = Wb + (size_t)(path*4 + 2)*36864;
    #pragma unroll
    for(int nt=0; nt<12; nt++){
      v4f acc = {0.f,0.f,0.f,0.f};
      int n = nt*16 + lr;
      #pragma unroll
      for(int c=0;c<6;c++){
        v8s bfr = *(const v8s*)&W[(size_t)n*D_ + c*32 + kb];
        acc = __builtin_amdgcn_mfma_f32_16x16x32_bf16(a[c], bfr, acc, 0,0,0);
      }
      int col = nt*16 + lr;
      v4us pk;
      pk[0]=f2bf(acc[0]); pk[1]=f2bf(acc[1]); pk[2]=f2bf(acc[2]); pk[3]=f2bf(acc[3]);
      *(v4us*)&Vstage[col*72 + sloc] = pk;
    }
    __syncthreads();
    unsigned short* dstV = V16 + (size_t)path*MD;
    size_t vg = (size_t)bidx*D_*S_ + sb;
    #pragma unroll
    for(int j=0;j<6;j++){
      int i = tid + j*256;
      int d = i>>3, s8 = (i&7)*8;
      *(v8s*)&dstV[vg + (size_t)d*S_ + s8] = *(const v8s*)&Vstage[d*72 + s8];
    }
  }
}

// ---------------- flash attention: split-K x2, fp8 QK + bf16 PV -------------
// grid (64,8,2) = 1024 blocks (2 halves x 32 q x 8 b x 2 paths), 512 thr.
// V DOUBLE-buffered (no PV lag), LDS 36.5 KB -> 4 blocks/CU; VGPR ~110 ->
// 4 waves/SIMD. Static softmax => split-K partials combine linearly in final.
#define KSTR8 200

__global__ __launch_bounds__(512,4) void attn_kernel(
    const unsigned char* __restrict__ QK8,
    const unsigned short* __restrict__ V16,
    unsigned short* __restrict__ Ob,
    float* __restrict__ Ls)
{
  __shared__ __align__(16) unsigned char  KL[2][32*KSTR8];   // 12.5 KB
  __shared__ __align__(16) unsigned short VL[2][192*32];     // 24 KB (36.5 KB)

  int flat = blockIdx.x + 64*blockIdx.y + 512*blockIdx.z;
  int w = (flat&7)*128 + (flat>>3);   // bijective on [0,1024)
  int qi   =  w       & 31;
  int b    = (w>>5)   & 7;
  int z    = (w>>8)   & 1;
  int half = (w>>9)   & 1;            // high bit: XCD KV set stays ~2.25 MB

  const size_t MDB = (size_t)M_*D_;
  const unsigned char* Q8 = QK8 + (size_t)z*2*MDB;
  const unsigned char* K8 = Q8 + MDB;
  const unsigned short* Vt = V16 + (size_t)z*MDB;
  unsigned short* O = Ob + (size_t)(z*2+half)*MDB;
  float* Lp = Ls + (size_t)(z*2+half)*M_;

  int q0 = qi*128;
  int tid = threadIdx.x, wid=tid>>6, lane=tid&63;
  int lr = lane&15, lg = lane>>4;
  size_t bK = (size_t)b*S_*D_;        // bytes (fp8)
  size_t bV = (size_t)b*D_*S_;        // shorts
  int qrow0 = q0 + wid*16;

  bool isK = wid < 4;
  int kt256 = tid & 255;
  int ksR = kt256>>3, ksC = (kt256&7)*24;
  int kLds = ksR*KSTR8 + ksC;
  int voff[3], vLds[3];
  #pragma unroll
  for(int j=0;j<3;j++){
    int i = (tid & 255) + j*256;
    int vrow = i>>2, vin = (i&3)*16;
    voff[j] = vrow*4096 + ((vin ^ (((vrow>>1)&3)<<4))>>1);
    vLds[j] = i*16;
  }
  int vro = ((lg*16) ^ (((lr>>1)&3)<<4)) >> 1;

  long qf8[6];
  {
    const unsigned char* qp = Q8 + bK + (size_t)(qrow0 + lr)*D_;
    #pragma unroll
    for(int c=0;c<6;c++) qf8[c] = *(const long*)(qp + c*32 + lg*8);
  }
  float lsum = 0.f;
  v4f oacc[12];
  #pragma unroll
  for(int e=0;e<12;e++) oacc[e] = (v4f){0.f,0.f,0.f,0.f};

  ull k0, k1, k2;
  auto kissue = [&](int t){
    if(isK){
      const unsigned char* kg = K8 + bK + (size_t)t*6144 + ksR*192 + ksC;
      k0 = *(const ull*)(kg);
      k1 = *(const ull*)(kg+8);
      k2 = *(const ull*)(kg+16);
    }
  };
  auto kwrite = [&](int buf){
    if(isK){
      unsigned char* d = &KL[buf][kLds];
      *(ull*)(d)    = k0;
      *(ull*)(d+8)  = k1;
      *(ull*)(d+16) = k2;
    }
  };
  auto vissue = [&](int t, int buf){
    if(!isK){
      const unsigned short* vg = Vt + bV + (size_t)t*32;
      #pragma unroll
      for(int j=0;j<3;j++) GLL16(vg + voff[j], ((unsigned char*)&VL[buf][0]) + vLds[j]);
    }
  };
  auto do_qk = [&](int kcur, v4f sacc[2]){
    __builtin_amdgcn_s_setprio(1);
    #pragma unroll
    for(int ct=0; ct<2; ct++){
      v4f s = {0.f,0.f,0.f,0.f};
      const unsigned char* rb = &KL[kcur][(ct*16+lr)*KSTR8];
      #pragma unroll
      for(int c=0;c<6;c++){
        long kf8 = *(const long*)(rb + c*32 + lg*8);
        s = __builtin_amdgcn_mfma_f32_16x16x32_fp8_fp8(kf8, qf8[c], s, 0,0,0);
      }
      sacc[ct]=s;
    }
    __builtin_amdgcn_s_setprio(0);
  };
  auto do_softmax = [&](v4f sacc[2], v8s& pa){
    float p00=fexp2(sacc[0][0]), p01=fexp2(sacc[0][1]);
    float p02=fexp2(sacc[0][2]), p03=fexp2(sacc[0][3]);
    float p10=fexp2(sacc[1][0]), p11=fexp2(sacc[1][1]);
    float p12=fexp2(sacc[1][2]), p13=fexp2(sacc[1][3]);
    lsum += ((p00+p01)+(p02+p03)) + ((p10+p11)+(p12+p13));
    unsigned X0=cvtpk(p00,p01), X1=cvtpk(p02,p03);
    unsigned Y0=cvtpk(p10,p11), Y1=cvtpk(p12,p13);
    asm("v_permlane32_swap_b32 %0, %1" : "+v"(Y0), "+v"(X0));
    asm("v_permlane32_swap_b32 %0, %1" : "+v"(Y1), "+v"(X1));
    asm("v_permlane16_swap_b32 %0, %1" : "+v"(Y0), "+v"(X0));
    asm("v_permlane16_swap_b32 %0, %1" : "+v"(Y1), "+v"(X1));
    union{ v8s s; unsigned w[4]; } u;
    u.w[0] = X0;  u.w[1] = X1;  u.w[2] = Y0;  u.w[3] = Y1;
    pa = u.s;
  };
  auto do_pv = [&](int vcur, v8s pa){
    __builtin_amdgcn_s_setprio(1);
    #pragma unroll
    for(int e=0;e<12;e++){
      v8s vbf = *(const v8s*)&VL[vcur][(e*16+lr)*32 + vro];
      oacc[e] = __builtin_amdgcn_mfma_f32_16x16x32_bf16(pa, vbf, oacc[e], 0,0,0);
    }
    __builtin_amdgcn_s_setprio(0);
  };

  int t0 = half*64;
  kissue(t0);
  vissue(t0, 0);
  kwrite(0);
  asm volatile("s_waitcnt vmcnt(0)" ::: "memory");
  __syncthreads();

  for(int tt=0; tt<64; tt++){
    int t = t0 + tt;
    int cur = tt&1;
    if(tt<63){ kissue(t+1); vissue(t+1, cur^1); }
    __builtin_amdgcn_sched_barrier(0);

    v4f sacc[2];
    do_qk(cur, sacc);
    v8s pa;
    do_softmax(sacc, pa);
    do_pv(cur, pa);

    if(tt<63) kwrite(cur^1);
    asm volatile("s_waitcnt vmcnt(0)" ::: "memory");
    __syncthreads();
  }

  // epilogue: per-row lsum partial (fp32) + raw O partial (bf16)
  float ps = lsum;
  ps += __shfl_xor(ps, 16);
  ps += __shfl_xor(ps, 32);
  if(lane < 16){
    Lp[(size_t)b*S_ + qrow0 + lr] = ps;
  }
  size_t orow0 = ((size_t)b*S_ + qrow0 + lg*4)*D_;
  #pragma unroll
  for(int e=0;e<12;e++){
    #pragma unroll
    for(int r=0;r<4;r++){
      O[orow0 + (size_t)r*D_ + e*16 + lr] = f2bf(oacc[e][r]);
    }
  }
}

// ---------------- final: combine halves + column-half GEMM split ------------
// grid dim3(512,2). Block computes out cols [96h, 96h+96) for its 64 rows.
__global__ __launch_bounds__(256) void final_kernel(
  const float* __restrict__ x,
  const unsigned short* __restrict__ Ob,
  const float* __restrict__ Ls,
  const unsigned short* __restrict__ WoR,
  const unsigned short* __restrict__ WoW,
  float* __restrict__ out)
{
  const size_t MD = (size_t)M_*D_;
  int halfn = blockIdx.y;
  int tid=threadIdx.x, wid=tid>>6, lane=tid&63;
  int lr=lane&15, lg=lane>>4, kb=lg*8;
  int m0 = blockIdx.x*64 + wid*16;
  int arow = m0 + lr;

  v8s ar[6], aw[6];
  #pragma unroll
  for(int path=0; path<2; path++){
    const unsigned short* O0 = Ob + (size_t)path*2*MD;
    const unsigned short* O1 = O0 + MD;
    const float* L0 = Ls + (size_t)path*2*M_;
    const float* L1 = L0 + M_;
    float inv = 1.0f/(L0[arow] + L1[arow]);
    #pragma unroll
    for(int c=0;c<6;c++){
      v8s x0 = *(const v8s*)&O0[(size_t)arow*D_ + c*32 + kb];
      v8s x1 = *(const v8s*)&O1[(size_t)arow*D_ + c*32 + kb];
      v8s t;
      #pragma unroll
      for(int j=0;j<8;j++){
        float f = (bf2f(x0[j]) + bf2f(x1[j])) * inv;
        t[j] = (short)f2bf(f);
      }
      if(path==0) ar[c]=t; else aw[c]=t;
    }
  }

  int bidx = m0 / S_;
  float rf = x[(size_t)bidx*S_*D_ + 156];
  float wf = x[(size_t)bidx*S_*D_ + 157];
  #pragma unroll
  for(int ntl=0; ntl<6; ntl++){
    int nt = halfn*6 + ntl;
    v4f accR={0.f,0.f,0.f,0.f}, accW={0.f,0.f,0.f,0.f};
    int n = nt*16 + lr;
    #pragma unroll
    for(int c=0;c<6;c++){
      v8s br = *(const v8s*)&WoR[(size_t)n*D_ + c*32 + kb];
      accR = __builtin_amdgcn_mfma_f32_16x16x32_bf16(ar[c], br, accR,0,0,0);
      v8s bw = *(const v8s*)&WoW[(size_t)n*D_ + c*32 + kb];
      accW = __builtin_amdgcn_mfma_f32_16x16x32_bf16(aw[c], bw, accW,0,0,0);
    }
    #pragma unroll
    for(int r=0;r<4;r++){
      int row = m0 + lg*4 + r;
      int col = nt*16 + lr;
      float xv = x[(size_t)row*D_ + col];
      float val = xv + rf*(accR[r]-xv) + wf*(accW[r]-xv);
      if(col==156||col==157) val = 0.f;
      else if(col==158) val = rf+wf;
      out[(size_t)row*D_ + col] = val;
    }
  }
}

extern "C" void kernel_launch(void* const* d_in, const int* in_sizes, int n_in,
                              void* d_out, int out_size, void* d_ws, size_t ws_size,
                              hipStream_t stream) {
  const float* x = (const float*)d_in[0];
  char* wsb = (char*)d_ws;
  const size_t WSZ = 36864;
  const size_t MDB = (size_t)M_*D_;
  unsigned short* Wb  = (unsigned short*)wsb;                        // 0.59 MB
  unsigned char*  QK8 = (unsigned char*)(wsb + 8*WSZ*2);             // 25.2 MB
  unsigned short* V16 = (unsigned short*)(wsb + 8*WSZ*2 + 4*MDB);    // 25.2 MB
  unsigned short* Ob  = V16 + 2*MDB;                                 // 50.3 MB (4x MD bf16)
  float*          Ls  = (float*)(Ob + 4*MDB);                        // 0.5 MB

  cvt_w_kernel<<<dim3(144,8),256,0,stream>>>(
      (const float*)d_in[1],(const float*)d_in[2],(const float*)d_in[3],(const float*)d_in[4],
      (const float*)d_in[5],(const float*)d_in[6],(const float*)d_in[7],(const float*)d_in[8], Wb);

  proj_kernel<<<dim3(512,2),256,0,stream>>>(x, Wb, QK8, V16);
  attn_kernel<<<dim3(64,8,2),512,0,stream>>>(QK8, V16, Ob, Ls);
  final_kernel<<<dim3(512,2),256,0,stream>>>(x, Ob, Ls,
                                             Wb+3*WSZ, Wb+7*WSZ, (float*)d_out);
}

// Round 26
// 322.533 us; speedup vs baseline: 1.0141x; 1.0141x over previous
//
#include <hip/hip_runtime.h>
#include <stdint.h>

#define B_ 8
#define S_ 4096
#define D_ 192
#define M_ (B_*S_)

typedef short v8s __attribute__((ext_vector_type(8)));
typedef float v4f __attribute__((ext_vector_type(4)));
typedef unsigned short v4us __attribute__((ext_vector_type(4)));
typedef unsigned long long ull;

static __device__ __forceinline__ unsigned short f2bf(float f){
  union{float f; unsigned u;} v; v.f=f;
  unsigned u = v.u;
  unsigned r = (u + 0x7fffu + ((u>>16)&1u))>>16;
  return (unsigned short)r;
}
static __device__ __forceinline__ float bf2f(unsigned short s){
  union{unsigned u; float f;} v; v.u = ((unsigned)s)<<16; return v.f;
}
static __device__ __forceinline__ float fexp2(float x){
  return __builtin_amdgcn_exp2f(x);
}
static __device__ __forceinline__ unsigned cvtpk(float lo, float hi){
  unsigned r;
  asm("v_cvt_pk_bf16_f32 %0, %1, %2" : "=v"(r) : "v"(lo), "v"(hi));
  return r;
}

// ---- fp8 e4m3fn pack ----
static __device__ __forceinline__ unsigned sw_fp8(float x){
  union{float f; unsigned u;} v; v.f = x;
  unsigned s = (v.u >> 24) & 0x80u;
  float a = fabsf(x);
  if (a < 0.001953125f) return s;
  if (a >= 240.f) return s | 0x7Eu;
  if (a < 0.015625f) {
    int m = (int)(a*512.f + 0.5f); if(m>7) m=7;
    return s | (unsigned)m;
  }
  int e = (int)((v.u >> 23) & 0xff) - 127;
  unsigned mant = (v.u >> 20) & 0x7u;
  unsigned rest = v.u & 0xFFFFFu;
  if (rest > 0x80000u || (rest == 0x80000u && (mant&1u))) mant++;
  unsigned ee = (unsigned)(e + 7);
  if (mant == 8u){ mant = 0u; ee++; }
  return s | (ee<<3) | mant;
}
template<bool HI>
static __device__ __forceinline__ unsigned pk8(float a, float b, unsigned old){
#if __has_builtin(__builtin_amdgcn_cvt_pk_fp8_f32)
  return __builtin_amdgcn_cvt_pk_fp8_f32(a, b, old, HI);
#else
  unsigned p = sw_fp8(a) | (sw_fp8(b)<<8);
  return HI ? ((old & 0x0000FFFFu) | (p<<16)) : ((old & 0xFFFF0000u) | p);
#endif
}

typedef const __attribute__((address_space(1))) unsigned int gu32;
typedef __attribute__((address_space(3))) unsigned int lu32;
#define GLL16(gp, lp) __builtin_amdgcn_global_load_lds((gu32*)(gp), (lu32*)(lp), 16, 0, 0)

// ---------------- weight conversion fp32 -> bf16 ----------------
__global__ void cvt_w_kernel(const float* w0,const float* w1,const float* w2,const float* w3,
                             const float* w4,const float* w5,const float* w6,const float* w7,
                             unsigned short* dst){
  int w = blockIdx.y;
  const float* src;
  switch(w){
    case 0: src=w0; break; case 1: src=w1; break; case 2: src=w2; break; case 3: src=w3; break;
    case 4: src=w4; break; case 5: src=w5; break; case 6: src=w6; break; default: src=w7; break;
  }
  int i = blockIdx.x*256 + threadIdx.x;
  float v = src[i];
  if(w==0 || w==4 || w==1 || w==5) v *= 0.32267249f;   // sqrt(log2(e)/sqrt(192))
  dst[(size_t)w*36864 + i] = f2bf(v);
}

// ---------------- fused QKV projection, split by path ----------------
__global__ __launch_bounds__(256) void proj_kernel(
    const float* __restrict__ x, const unsigned short* __restrict__ Wb,
    unsigned char* __restrict__ QK8, unsigned short* __restrict__ V16)
{
  __shared__ __align__(16) unsigned short Vstage[192*72];   // 27.6 KB
  const size_t MDB = (size_t)M_*D_;
  const size_t MD  = (size_t)M_*D_;
  int path = blockIdx.y;
  int tid = threadIdx.x;
  int wid = tid>>6, lane = tid&63;
  int lr = lane&15, lg = lane>>4, kb = lg*8;
  int m0 = blockIdx.x*64 + wid*16;
  int row = m0 + lr;

  v8s a[6];
  #pragma unroll
  for(int c=0;c<6;c++){
    const float* xp = &x[(size_t)row*D_ + c*32 + kb];
    float4 f0 = *(const float4*)xp;
    float4 f1 = *(const float4*)(xp+4);
    v8s t;
    t[0]=(short)f2bf(f0.x); t[1]=(short)f2bf(f0.y); t[2]=(short)f2bf(f0.z); t[3]=(short)f2bf(f0.w);
    t[4]=(short)f2bf(f1.x); t[5]=(short)f2bf(f1.y); t[6]=(short)f2bf(f1.z); t[7]=(short)f2bf(f1.w);
    a[c]=t;
  }
  int bidx = m0 / S_;
  int sb   = (blockIdx.x*64) % S_;
  int sloc = wid*16 + lg*4;

  unsigned char* dstQ8 = QK8 + (size_t)path*2*MDB;
  for(int which=0; which<2; which++){
    const unsigned short* W = Wb + (size_t)(path*4 + which)*36864;
    unsigned char* dst = which==0 ? dstQ8 : dstQ8 + MDB;
    #pragma unroll
    for(int nt=0; nt<12; nt++){
      v4f acc = {0.f,0.f,0.f,0.f};
      int n = nt*16 + lr;
      #pragma unroll
      for(int c=0;c<6;c++){
        v8s bfr = *(const v8s*)&W[(size_t)n*D_ + c*32 + kb];
        acc = __builtin_amdgcn_mfma_f32_16x16x32_bf16(a[c], bfr, acc, 0,0,0);
      }
      int col = nt*16 + lr;
      int r0 = m0 + lg*4;
      #pragma unroll
      for(int r=0;r<4;r++){
        unsigned p = pk8<false>(acc[r], 0.f, 0u);
        dst[(size_t)(r0+r)*D_ + col] = (unsigned char)(p & 0xFF);
      }
    }
  }
  // V -> bf16 LDS transpose stage -> coalesced stores
  {
    const unsigned short* W = Wb + (size_t)(path*4 + 2)*36864;
    #pragma unroll
    for(int nt=0; nt<12; nt++){
      v4f acc = {0.f,0.f,0.f,0.f};
      int n = nt*16 + lr;
      #pragma unroll
      for(int c=0;c<6;c++){
        v8s bfr = *(const v8s*)&W[(size_t)n*D_ + c*32 + kb];
        acc = __builtin_amdgcn_mfma_f32_16x16x32_bf16(a[c], bfr, acc, 0,0,0);
      }
      int col = nt*16 + lr;
      v4us pk;
      pk[0]=f2bf(acc[0]); pk[1]=f2bf(acc[1]); pk[2]=f2bf(acc[2]); pk[3]=f2bf(acc[3]);
      *(v4us*)&Vstage[col*72 + sloc] = pk;
    }
    __syncthreads();
    unsigned short* dstV = V16 + (size_t)path*MD;
    size_t vg = (size_t)bidx*D_*S_ + sb;
    #pragma unroll
    for(int j=0;j<6;j++){
      int i = tid + j*256;
      int d = i>>3, s8 = (i&7)*8;
      *(v8s*)&dstV[vg + (size_t)d*S_ + s8] = *(const v8s*)&Vstage[d*72 + s8];
    }
  }
}

// ---------------- flash attention + fused Wo projection ---------------------
// grid (32,8,2), 512 thr (8w x 16q). Full-K, round-23 pipeline (184.5 us).
// PV computed SWAPPED: mfma(V^T-frag, P-frag) -> oacc holds O^T fragments
// (row=d, col=q=lr). lsum inverse becomes lane-local; the validated
// cvtpk+permlane repack turns normalized O^T C-frags into A-frags of O with
// k=d, feeding a 72-MFMA epilogue GEMM against L2-hot Wo. Writes R (post-
// projection, bf16) -> final becomes pure elementwise streaming.
#define KSTR8 200

__global__ __launch_bounds__(512,4) void attn_kernel(
    const unsigned char* __restrict__ QK8,
    const unsigned short* __restrict__ V16,
    const unsigned short* __restrict__ Wb,
    unsigned short* __restrict__ Rb)
{
  __shared__ __align__(16) unsigned char  KL[2][32*KSTR8];   // 12.5 KB
  __shared__ __align__(16) unsigned short VL[3][192*32];     // 36 KB (48.5 KB)

  int flat = blockIdx.x + 32*blockIdx.y + 256*blockIdx.z;
  int w = (flat&7)*64 + (flat>>3);   // bijective on [0,512)
  int qi = w & 31;
  int b  = (w>>5) & 7;
  int z  = w>>8;

  const size_t MDB = (size_t)M_*D_;
  const unsigned char* Q8 = QK8 + (size_t)z*2*MDB;
  const unsigned char* K8 = Q8 + MDB;
  const unsigned short* Vt = V16 + (size_t)z*MDB;
  unsigned short* R = Rb + (size_t)z*MDB;

  int q0 = qi*128;
  int tid = threadIdx.x, wid=tid>>6, lane=tid&63;
  int lr = lane&15, lg = lane>>4;
  size_t bK = (size_t)b*S_*D_;        // bytes (fp8)
  size_t bV = (size_t)b*D_*S_;        // shorts
  int qrow0 = q0 + wid*16;

  bool isK = wid < 4;
  int kt256 = tid & 255;
  int ksR = kt256>>3, ksC = (kt256&7)*24;
  int kLds = ksR*KSTR8 + ksC;
  int voff[3], vLds[3];
  #pragma unroll
  for(int j=0;j<3;j++){
    int i = (tid & 255) + j*256;
    int vrow = i>>2, vin = (i&3)*16;
    voff[j] = vrow*4096 + ((vin ^ (((vrow>>1)&3)<<4))>>1);
    vLds[j] = i*16;
  }
  int vro = ((lg*16) ^ (((lr>>1)&3)<<4)) >> 1;

  long qf8[6];
  {
    const unsigned char* qp = Q8 + bK + (size_t)(qrow0 + lr)*D_;
    #pragma unroll
    for(int c=0;c<6;c++) qf8[c] = *(const long*)(qp + c*32 + lg*8);
  }
  float lsum = 0.f;
  v4f oacc[12];                       // O^T fragments: [d=e*16+lg*4+r][q=lr]
  #pragma unroll
  for(int e=0;e<12;e++) oacc[e] = (v4f){0.f,0.f,0.f,0.f};

  ull k0, k1, k2;
  auto kissue = [&](int t){
    if(isK){
      const unsigned char* kg = K8 + bK + (size_t)t*6144 + ksR*192 + ksC;
      k0 = *(const ull*)(kg);
      k1 = *(const ull*)(kg+8);
      k2 = *(const ull*)(kg+16);
    }
  };
  auto kwrite = [&](int buf){
    if(isK){
      unsigned char* d = &KL[buf][kLds];
      *(ull*)(d)    = k0;
      *(ull*)(d+8)  = k1;
      *(ull*)(d+16) = k2;
    }
  };
  auto vissue = [&](int t, int buf){
    if(!isK){
      const unsigned short* vg = Vt + bV + (size_t)t*32;
      #pragma unroll
      for(int j=0;j<3;j++) GLL16(vg + voff[j], ((unsigned char*)&VL[buf][0]) + vLds[j]);
    }
  };
  auto do_qk = [&](int kcur, v4f sacc[2]){
    __builtin_amdgcn_s_setprio(1);
    #pragma unroll
    for(int ct=0; ct<2; ct++){
      v4f s = {0.f,0.f,0.f,0.f};
      const unsigned char* rb = &KL[kcur][(ct*16+lr)*KSTR8];
      #pragma unroll
      for(int c=0;c<6;c++){
        long kf8 = *(const long*)(rb + c*32 + lg*8);
        s = __builtin_amdgcn_mfma_f32_16x16x32_fp8_fp8(kf8, qf8[c], s, 0,0,0);
      }
      sacc[ct]=s;
    }
    __builtin_amdgcn_s_setprio(0);
  };
  auto do_softmax = [&](v4f sacc[2], v8s& pa){
    float p00=fexp2(sacc[0][0]), p01=fexp2(sacc[0][1]);
    float p02=fexp2(sacc[0][2]), p03=fexp2(sacc[0][3]);
    float p10=fexp2(sacc[1][0]), p11=fexp2(sacc[1][1]);
    float p12=fexp2(sacc[1][2]), p13=fexp2(sacc[1][3]);
    lsum += ((p00+p01)+(p02+p03)) + ((p10+p11)+(p12+p13));
    unsigned X0=cvtpk(p00,p01), X1=cvtpk(p02,p03);
    unsigned Y0=cvtpk(p10,p11), Y1=cvtpk(p12,p13);
    asm("v_permlane32_swap_b32 %0, %1" : "+v"(Y0), "+v"(X0));
    asm("v_permlane32_swap_b32 %0, %1" : "+v"(Y1), "+v"(X1));
    asm("v_permlane16_swap_b32 %0, %1" : "+v"(Y0), "+v"(X0));
    asm("v_permlane16_swap_b32 %0, %1" : "+v"(Y1), "+v"(X1));
    union{ v8s s; unsigned w[4]; } u;
    u.w[0] = X0;  u.w[1] = X1;  u.w[2] = Y0;  u.w[3] = Y1;
    pa = u.s;
  };
  auto do_pv = [&](int vcur, v8s pa){
    __builtin_amdgcn_s_setprio(1);
    #pragma unroll
    for(int e=0;e<12;e++){
      v8s vbf = *(const v8s*)&VL[vcur][(e*16+lr)*32 + vro];
      // SWAPPED: A=V^T frag (row=d), B=P frag (col=q) -> C = O^T
      oacc[e] = __builtin_amdgcn_mfma_f32_16x16x32_bf16(vbf, pa, oacc[e], 0,0,0);
    }
    __builtin_amdgcn_s_setprio(0);
  };

  kissue(0);
  vissue(0, 0);
  kwrite(0);
  asm volatile("s_waitcnt vmcnt(0)" ::: "memory");
  __syncthreads();

  v8s pa_prev;
  {
    v4f sacc[2];
    do_qk(0, sacc);
    kissue(1);
    vissue(1, 1);
    __builtin_amdgcn_sched_barrier(0);
    do_softmax(sacc, pa_prev);
    kwrite(1);
    asm volatile("s_waitcnt vmcnt(0)" ::: "memory");
    __syncthreads();
  }

  for(int t=1; t<128; t++){
    v4f sacc[2];
    do_qk(t&1, sacc);
    if(t<127){ kissue(t+1); vissue(t+1, (t+1)%3); }
    __builtin_amdgcn_sched_barrier(0);
    do_pv((t-1)%3, pa_prev);
    do_softmax(sacc, pa_prev);
    if(t<127) kwrite((t+1)&1);
    asm volatile("s_waitcnt vmcnt(0)" ::: "memory");
    __syncthreads();
  }
  do_pv(127%3, pa_prev);

  // ---- fused epilogue: normalize (lane-local!), repack, R = O @ Wo^T ----
  float ps = lsum;
  ps += __shfl_xor(ps, 16);
  ps += __shfl_xor(ps, 32);
  float iv = 1.0f/ps;                  // q = lr: directly usable on O^T frags

  v8s oT[6];                           // A-frags of O: [q=lr][k=d=c*32+lg*8+j]
  #pragma unroll
  for(int c=0;c<6;c++){
    v4f lo = oacc[2*c], hi = oacc[2*c+1];
    unsigned X0=cvtpk(lo[0]*iv, lo[1]*iv), X1=cvtpk(lo[2]*iv, lo[3]*iv);
    unsigned Y0=cvtpk(hi[0]*iv, hi[1]*iv), Y1=cvtpk(hi[2]*iv, hi[3]*iv);
    asm("v_permlane32_swap_b32 %0, %1" : "+v"(Y0), "+v"(X0));
    asm("v_permlane32_swap_b32 %0, %1" : "+v"(Y1), "+v"(X1));
    asm("v_permlane16_swap_b32 %0, %1" : "+v"(Y0), "+v"(X0));
    asm("v_permlane16_swap_b32 %0, %1" : "+v"(Y1), "+v"(X1));
    union{ v8s s; unsigned w[4]; } u;
    u.w[0] = X0;  u.w[1] = X1;  u.w[2] = Y0;  u.w[3] = Y1;
    oT[c] = u.s;
  }
  const unsigned short* Wo = Wb + (size_t)(z*4+3)*36864;
  size_t rrow0 = ((size_t)b*S_ + qrow0 + lg*4)*D_;
  #pragma unroll
  for(int nt=0; nt<12; nt++){
    v4f acc = {0.f,0.f,0.f,0.f};
    int n = nt*16 + lr;
    #pragma unroll
    for(int c=0;c<6;c++){
      v8s bw = *(const v8s*)&Wo[(size_t)n*D_ + c*32 + lg*8];
      acc = __builtin_amdgcn_mfma_f32_16x16x32_bf16(oT[c], bw, acc, 0,0,0);
    }
    #pragma unroll
    for(int r=0;r<4;r++){
      R[rrow0 + (size_t)r*D_ + nt*16 + lr] = f2bf(acc[r]);
    }
  }
}

// ---------------- final: pure elementwise combine + column fixes ------------
// out = x + rf*(Rr - x) + wf*(Rw - x); cols 156/157 -> 0, 158 -> rf+wf.
__global__ __launch_bounds__(256) void final_kernel(
  const float* __restrict__ x,
  const unsigned short* __restrict__ Rr,
  const unsigned short* __restrict__ Rw,
  float* __restrict__ out)
{
  const int NG = M_*D_/4;              // 4-elem groups
  int gid = blockIdx.x*256 + threadIdx.x;
  for(int g = gid; g < NG; g += 2048*256){
    int e0 = g*4;
    int row = e0 / D_;
    int col = e0 % D_;
    int b = row >> 12;                 // row / 4096
    size_t xb = (size_t)b*S_*D_;
    float rf = x[xb + 156];
    float wf = x[xb + 157];
    float4 xv = *(const float4*)&x[e0];
    v4us r4 = *(const v4us*)&Rr[e0];
    v4us w4 = *(const v4us*)&Rw[e0];
    float o[4];
    #pragma unroll
    for(int j=0;j<4;j++){
      float xvj = (&xv.x)[j];
      float val = xvj + rf*(bf2f(r4[j]) - xvj) + wf*(bf2f(w4[j]) - xvj);
      int cj = col + j;
      if(cj==156||cj==157) val = 0.f;
      else if(cj==158) val = rf+wf;
      o[j] = val;
    }
    *(float4*)&out[e0] = *(float4*)o;
  }
}

extern "C" void kernel_launch(void* const* d_in, const int* in_sizes, int n_in,
                              void* d_out, int out_size, void* d_ws, size_t ws_size,
                              hipStream_t stream) {
  const float* x = (const float*)d_in[0];
  char* wsb = (char*)d_ws;
  const size_t WSZ = 36864;
  const size_t MDB = (size_t)M_*D_;
  unsigned short* Wb  = (unsigned short*)wsb;                        // 0.59 MB
  unsigned char*  QK8 = (unsigned char*)(wsb + 8*WSZ*2);             // 25.2 MB
  unsigned short* V16 = (unsigned short*)(wsb + 8*WSZ*2 + 4*MDB);    // 25.2 MB
  unsigned short* Rb  = V16 + 2*MDB;                                 // 25.2 MB

  cvt_w_kernel<<<dim3(144,8),256,0,stream>>>(
      (const float*)d_in[1],(const float*)d_in[2],(const float*)d_in[3],(const float*)d_in[4],
      (const float*)d_in[5],(const float*)d_in[6],(const float*)d_in[7],(const float*)d_in[8], Wb);

  proj_kernel<<<dim3(512,2),256,0,stream>>>(x, Wb, QK8, V16);
  attn_kernel<<<dim3(32,8,2),512,0,stream>>>(QK8, V16, Wb, Rb);
  final_kernel<<<2048,256,0,stream>>>(x, Rb, Rb + MDB, (float*)d_out);
}

// Round 27
// 309.897 us; speedup vs baseline: 1.0554x; 1.0408x over previous
//
#include <hip/hip_runtime.h>
#include <stdint.h>

#define B_ 8
#define S_ 4096
#define D_ 192
#define M_ (B_*S_)
#define VTILE 7680   // V fp8 tile image: 192 rows x (32 s + 8 pad) bytes

typedef short v8s __attribute__((ext_vector_type(8)));
typedef float v4f __attribute__((ext_vector_type(4)));
typedef unsigned short v4us __attribute__((ext_vector_type(4)));
typedef unsigned long long ull;

static __device__ __forceinline__ unsigned short f2bf(float f){
  union{float f; unsigned u;} v; v.f=f;
  unsigned u = v.u;
  unsigned r = (u + 0x7fffu + ((u>>16)&1u))>>16;
  return (unsigned short)r;
}
static __device__ __forceinline__ float fexp2(float x){
  return __builtin_amdgcn_exp2f(x);
}
static __device__ __forceinline__ unsigned cvtpk(float lo, float hi){
  unsigned r;
  asm("v_cvt_pk_bf16_f32 %0, %1, %2" : "=v"(r) : "v"(lo), "v"(hi));
  return r;
}
static __device__ __forceinline__ float asf(unsigned u){
  union{unsigned u; float f;} v; v.u=u; return v.f;
}

// ---- fp8 e4m3fn pack ----
static __device__ __forceinline__ unsigned sw_fp8(float x){
  union{float f; unsigned u;} v; v.f = x;
  unsigned s = (v.u >> 24) & 0x80u;
  float a = fabsf(x);
  if (a < 0.001953125f) return s;
  if (a >= 240.f) return s | 0x7Eu;
  if (a < 0.015625f) {
    int m = (int)(a*512.f + 0.5f); if(m>7) m=7;
    return s | (unsigned)m;
  }
  int e = (int)((v.u >> 23) & 0xff) - 127;
  unsigned mant = (v.u >> 20) & 0x7u;
  unsigned rest = v.u & 0xFFFFFu;
  if (rest > 0x80000u || (rest == 0x80000u && (mant&1u))) mant++;
  unsigned ee = (unsigned)(e + 7);
  if (mant == 8u){ mant = 0u; ee++; }
  return s | (ee<<3) | mant;
}
template<bool HI>
static __device__ __forceinline__ unsigned pk8(float a, float b, unsigned old){
#if __has_builtin(__builtin_amdgcn_cvt_pk_fp8_f32)
  return __builtin_amdgcn_cvt_pk_fp8_f32(a, b, old, HI);
#else
  unsigned p = sw_fp8(a) | (sw_fp8(b)<<8);
  return HI ? ((old & 0x0000FFFFu) | (p<<16)) : ((old & 0xFFFF0000u) | p);
#endif
}

typedef const __attribute__((address_space(1))) unsigned int gu32;
typedef __attribute__((address_space(3))) unsigned int lu32;
#define GLL16(gp, lp) __builtin_amdgcn_global_load_lds((gu32*)(gp), (lu32*)(lp), 16, 0, 0)

// ---------------- weight conversion fp32 -> bf16 ----------------
__global__ void cvt_w_kernel(const float* w0,const float* w1,const float* w2,const float* w3,
                             const float* w4,const float* w5,const float* w6,const float* w7,
                             unsigned short* dst){
  int w = blockIdx.y;
  const float* src;
  switch(w){
    case 0: src=w0; break; case 1: src=w1; break; case 2: src=w2; break; case 3: src=w3; break;
    case 4: src=w4; break; case 5: src=w5; break; case 6: src=w6; break; default: src=w7; break;
  }
  int i = blockIdx.x*256 + threadIdx.x;
  float v = src[i];
  if(w==0 || w==4 || w==1 || w==5) v *= 0.32267249f;   // sqrt(log2(e)/sqrt(192))
  dst[(size_t)w*36864 + i] = f2bf(v);
}

// ---------------- fused QKV projection, split by path ----------------
// Q8,K8 fp8 [row][192]; V fp8 tile images [b][128 tiles][192][40B] (linear,
// DMA-ready, bank-analyzed: b64 reads land 2-way uniform -> free).
__global__ __launch_bounds__(256) void proj_kernel(
    const float* __restrict__ x, const unsigned short* __restrict__ Wb,
    unsigned char* __restrict__ QK8, unsigned char* __restrict__ V8)
{
  __shared__ __align__(16) unsigned char Vstage8[2*VTILE];   // 15.4 KB
  const size_t MDB = (size_t)M_*D_;
  int path = blockIdx.y;
  int tid = threadIdx.x;
  int wid = tid>>6, lane = tid&63;
  int lr = lane&15, lg = lane>>4, kb = lg*8;
  int m0 = blockIdx.x*64 + wid*16;
  int row = m0 + lr;

  v8s a[6];
  #pragma unroll
  for(int c=0;c<6;c++){
    const float* xp = &x[(size_t)row*D_ + c*32 + kb];
    float4 f0 = *(const float4*)xp;
    float4 f1 = *(const float4*)(xp+4);
    v8s t;
    t[0]=(short)f2bf(f0.x); t[1]=(short)f2bf(f0.y); t[2]=(short)f2bf(f0.z); t[3]=(short)f2bf(f0.w);
    t[4]=(short)f2bf(f1.x); t[5]=(short)f2bf(f1.y); t[6]=(short)f2bf(f1.z); t[7]=(short)f2bf(f1.w);
    a[c]=t;
  }
  int bidx = m0 / S_;
  int sb   = (blockIdx.x*64) % S_;       // block s-base (64 s = 2 tiles)
  int sloc = wid*16 + lg*4;              // local s (0..63)

  unsigned char* dstQ8 = QK8 + (size_t)path*2*MDB;
  for(int which=0; which<2; which++){
    const unsigned short* W = Wb + (size_t)(path*4 + which)*36864;
    unsigned char* dst = which==0 ? dstQ8 : dstQ8 + MDB;
    #pragma unroll
    for(int nt=0; nt<12; nt++){
      v4f acc = {0.f,0.f,0.f,0.f};
      int n = nt*16 + lr;
      #pragma unroll
      for(int c=0;c<6;c++){
        v8s bfr = *(const v8s*)&W[(size_t)n*D_ + c*32 + kb];
        acc = __builtin_amdgcn_mfma_f32_16x16x32_bf16(a[c], bfr, acc, 0,0,0);
      }
      int col = nt*16 + lr;
      int r0 = m0 + lg*4;
      #pragma unroll
      for(int r=0;r<4;r++){
        unsigned p = pk8<false>(acc[r], 0.f, 0u);
        dst[(size_t)(r0+r)*D_ + col] = (unsigned char)(p & 0xFF);
      }
    }
  }
  // V -> fp8 tile-image stage -> linear copy to global
  {
    const unsigned short* W = Wb + (size_t)(path*4 + 2)*36864;
    int t2 = sloc >> 5, s32 = sloc & 31;
    #pragma unroll
    for(int nt=0; nt<12; nt++){
      v4f acc = {0.f,0.f,0.f,0.f};
      int n = nt*16 + lr;
      #pragma unroll
      for(int c=0;c<6;c++){
        v8s bfr = *(const v8s*)&W[(size_t)n*D_ + c*32 + kb];
        acc = __builtin_amdgcn_mfma_f32_16x16x32_bf16(a[c], bfr, acc, 0,0,0);
      }
      int col = nt*16 + lr;
      unsigned pk4 = pk8<false>(acc[0], acc[1], 0u);
      pk4 = pk8<true>(acc[2], acc[3], pk4);
      *(unsigned*)&Vstage8[t2*VTILE + col*40 + s32] = pk4;
    }
    __syncthreads();
    unsigned char* dstV = V8 + (size_t)path*((size_t)B_*128*VTILE)
                        + ((size_t)bidx*128 + (sb>>5))*VTILE;
    #pragma unroll
    for(int j=0;j<4;j++){
      int i = tid + j*256;                 // 960 chunks of 16B
      if(i<960) *(v8s*)&dstV[i*16] = *(const v8s*)&Vstage8[i*16];
    }
  }
}

// ---------------- flash attention: fp8 QK + fp8 PV, 8 waves x 16 q ----------
// grid (32,8,2) XCD-remapped, 512 thr. Full-K. Round-23 pipeline, V now fp8:
// per-wave LDS/tile 18KB -> 12KB. V LDS [192][40B] linear (2-way banks, no
// swizzle, DMA linear). P->fp8 repack = round-19-validated code.
#define KSTR8 200

__global__ __launch_bounds__(512,4) void attn_kernel(
    const unsigned char* __restrict__ QK8,
    const unsigned char* __restrict__ V8,
    unsigned short* __restrict__ Ob)
{
  __shared__ __align__(16) unsigned char KL[2][32*KSTR8];   // 12.5 KB
  __shared__ __align__(16) unsigned char VL8[3][VTILE];     // 22.5 KB (35 KB)

  int flat = blockIdx.x + 32*blockIdx.y + 256*blockIdx.z;
  int w = (flat&7)*64 + (flat>>3);   // bijective on [0,512)
  int qi = w & 31;
  int b  = (w>>5) & 7;
  int z  = w>>8;

  const size_t MDB = (size_t)M_*D_;
  const unsigned char* Q8 = QK8 + (size_t)z*2*MDB;
  const unsigned char* K8 = Q8 + MDB;
  const unsigned char* Vp = V8 + (size_t)z*((size_t)B_*128*VTILE);
  unsigned short* O = Ob + (size_t)z*MDB;

  int q0 = qi*128;
  int tid = threadIdx.x, wid=tid>>6, lane=tid&63;
  int lr = lane&15, lg = lane>>4;
  size_t bK = (size_t)b*S_*D_;        // bytes (fp8)
  int qrow0 = q0 + wid*16;

  bool isK = wid < 4;
  int kt256 = tid & 255;
  int ksR = kt256>>3, ksC = (kt256&7)*24;
  int kLds = ksR*KSTR8 + ksC;

  long qf8[6];
  {
    const unsigned char* qp = Q8 + bK + (size_t)(qrow0 + lr)*D_;
    #pragma unroll
    for(int c=0;c<6;c++) qf8[c] = *(const long*)(qp + c*32 + lg*8);
  }
  float lsum = 0.f;
  v4f oacc[12];
  #pragma unroll
  for(int e=0;e<12;e++) oacc[e] = (v4f){0.f,0.f,0.f,0.f};

  ull k0, k1, k2;
  auto kissue = [&](int t){
    if(isK){
      const unsigned char* kg = K8 + bK + (size_t)t*6144 + ksR*192 + ksC;
      k0 = *(const ull*)(kg);
      k1 = *(const ull*)(kg+8);
      k2 = *(const ull*)(kg+16);
    }
  };
  auto kwrite = [&](int buf){
    if(isK){
      unsigned char* d = &KL[buf][kLds];
      *(ull*)(d)    = k0;
      *(ull*)(d+8)  = k1;
      *(ull*)(d+16) = k2;
    }
  };
  auto vissue = [&](int t, int buf){
    if(!isK){
      const unsigned char* vg = Vp + ((size_t)b*128 + t)*VTILE;
      #pragma unroll
      for(int j=0;j<2;j++){
        int i = (tid&255) + j*256;         // 480 chunks of 16B
        if(i<480) GLL16(vg + i*16, &VL8[buf][i*16]);
      }
    }
  };
  auto do_qk = [&](int kcur, v4f sacc[2]){
    __builtin_amdgcn_s_setprio(1);
    #pragma unroll
    for(int ct=0; ct<2; ct++){
      v4f s = {0.f,0.f,0.f,0.f};
      const unsigned char* rb = &KL[kcur][(ct*16+lr)*KSTR8];
      #pragma unroll
      for(int c=0;c<6;c++){
        long kf8 = *(const long*)(rb + c*32 + lg*8);
        s = __builtin_amdgcn_mfma_f32_16x16x32_fp8_fp8(kf8, qf8[c], s, 0,0,0);
      }
      sacc[ct]=s;
    }
    __builtin_amdgcn_s_setprio(0);
  };
  auto do_softmax = [&](v4f sacc[2], long& pa8){
    float p00=fexp2(sacc[0][0]), p01=fexp2(sacc[0][1]);
    float p02=fexp2(sacc[0][2]), p03=fexp2(sacc[0][3]);
    float p10=fexp2(sacc[1][0]), p11=fexp2(sacc[1][1]);
    float p12=fexp2(sacc[1][2]), p13=fexp2(sacc[1][3]);
    lsum += ((p00+p01)+(p02+p03)) + ((p10+p11)+(p12+p13));
    unsigned X0=cvtpk(p00,p01), X1=cvtpk(p02,p03);
    unsigned Y0=cvtpk(p10,p11), Y1=cvtpk(p12,p13);
    asm("v_permlane32_swap_b32 %0, %1" : "+v"(Y0), "+v"(X0));
    asm("v_permlane32_swap_b32 %0, %1" : "+v"(Y1), "+v"(X1));
    asm("v_permlane16_swap_b32 %0, %1" : "+v"(Y0), "+v"(X0));
    asm("v_permlane16_swap_b32 %0, %1" : "+v"(Y1), "+v"(X1));
    // bf16 words {X0,X1,Y0,Y1} = k  lg*8+0..7 -> 8 fp8 bytes (round-19 path)
    float e0 = asf(X0<<16), e1 = asf(X0 & 0xffff0000u);
    float e2 = asf(X1<<16), e3 = asf(X1 & 0xffff0000u);
    float e4 = asf(Y0<<16), e5 = asf(Y0 & 0xffff0000u);
    float e6 = asf(Y1<<16), e7 = asf(Y1 & 0xffff0000u);
    unsigned lo = pk8<false>(e0,e1,0u); lo = pk8<true>(e2,e3,lo);
    unsigned hi = pk8<false>(e4,e5,0u); hi = pk8<true>(e6,e7,hi);
    pa8 = (long)(((ull)hi<<32) | (ull)lo);
  };
  auto do_pv = [&](int vcur, long pa8){
    __builtin_amdgcn_s_setprio(1);
    #pragma unroll
    for(int e=0;e<12;e++){
      long vb8 = *(const long*)&VL8[vcur][(e*16+lr)*40 + lg*8];
      oacc[e] = __builtin_amdgcn_mfma_f32_16x16x32_fp8_fp8(pa8, vb8, oacc[e], 0,0,0);
    }
    __builtin_amdgcn_s_setprio(0);
  };

  kissue(0);
  vissue(0, 0);
  kwrite(0);
  asm volatile("s_waitcnt vmcnt(0)" ::: "memory");
  __syncthreads();

  long pa_prev;
  {
    v4f sacc[2];
    do_qk(0, sacc);
    kissue(1);
    vissue(1, 1);
    __builtin_amdgcn_sched_barrier(0);
    do_softmax(sacc, pa_prev);
    kwrite(1);
    asm volatile("s_waitcnt vmcnt(0)" ::: "memory");
    __syncthreads();
  }

  for(int t=1; t<128; t++){
    v4f sacc[2];
    do_qk(t&1, sacc);
    if(t<127){ kissue(t+1); vissue(t+1, (t+1)%3); }
    __builtin_amdgcn_sched_barrier(0);
    do_pv((t-1)%3, pa_prev);
    do_softmax(sacc, pa_prev);
    if(t<127) kwrite((t+1)&1);
    asm volatile("s_waitcnt vmcnt(0)" ::: "memory");
    __syncthreads();
  }
  do_pv(127%3, pa_prev);

  // epilogue: per-lane sums (q-row = lr) -> row inverses -> O write (bf16)
  float ps = lsum;
  ps += __shfl_xor(ps, 16);
  ps += __shfl_xor(ps, 32);
  float iv = 1.0f/ps;
  float invr[4];
  #pragma unroll
  for(int r=0;r<4;r++) invr[r] = __shfl(iv, lg*4+r, 16);
  size_t orow0 = ((size_t)b*S_ + qrow0 + lg*4)*D_;
  #pragma unroll
  for(int e=0;e<12;e++){
    #pragma unroll
    for(int r=0;r<4;r++){
      O[orow0 + (size_t)r*D_ + e*16 + lr] = f2bf(oacc[e][r]*invr[r]);
    }
  }
}

// ---------------- final: column-half GEMM split (round-24 form) -------------
__global__ __launch_bounds__(256) void final_kernel(
  const float* __restrict__ x,
  const unsigned short* __restrict__ Or,
  const unsigned short* __restrict__ Ow,
  const unsigned short* __restrict__ WoR,
  const unsigned short* __restrict__ WoW,
  float* __restrict__ out)
{
  int halfn = blockIdx.y;
  int tid=threadIdx.x, wid=tid>>6, lane=tid&63;
  int lr=lane&15, lg=lane>>4, kb=lg*8;
  int m0 = blockIdx.x*64 + wid*16;
  int arow = m0 + lr;
  v8s ar[6], aw[6];
  #pragma unroll
  for(int c=0;c<6;c++){
    ar[c] = *(const v8s*)&Or[(size_t)arow*D_ + c*32 + kb];
    aw[c] = *(const v8s*)&Ow[(size_t)arow*D_ + c*32 + kb];
  }
  int bidx = m0 / S_;
  float rf = x[(size_t)bidx*S_*D_ + 156];
  float wf = x[(size_t)bidx*S_*D_ + 157];
  #pragma unroll
  for(int ntl=0; ntl<6; ntl++){
    int nt = halfn*6 + ntl;
    v4f accR={0.f,0.f,0.f,0.f}, accW={0.f,0.f,0.f,0.f};
    int n = nt*16 + lr;
    #pragma unroll
    for(int c=0;c<6;c++){
      v8s br = *(const v8s*)&WoR[(size_t)n*D_ + c*32 + kb];
      accR = __builtin_amdgcn_mfma_f32_16x16x32_bf16(ar[c], br, accR,0,0,0);
      v8s bw = *(const v8s*)&WoW[(size_t)n*D_ + c*32 + kb];
      accW = __builtin_amdgcn_mfma_f32_16x16x32_bf16(aw[c], bw, accW,0,0,0);
    }
    #pragma unroll
    for(int r=0;r<4;r++){
      int row = m0 + lg*4 + r;
      int col = nt*16 + lr;
      float xv = x[(size_t)row*D_ + col];
      float val = xv + rf*(accR[r]-xv) + wf*(accW[r]-xv);
      if(col==156||col==157) val = 0.f;
      else if(col==158) val = rf+wf;
      out[(size_t)row*D_ + col] = val;
    }
  }
}

extern "C" void kernel_launch(void* const* d_in, const int* in_sizes, int n_in,
                              void* d_out, int out_size, void* d_ws, size_t ws_size,
                              hipStream_t stream) {
  const float* x = (const float*)d_in[0];
  char* wsb = (char*)d_ws;
  const size_t WSZ = 36864;
  const size_t MDB = (size_t)M_*D_;
  const size_t V8SZ = (size_t)2*B_*128*VTILE;                  // 15.7 MB
  unsigned short* Wb  = (unsigned short*)wsb;                  // 0.59 MB
  unsigned char*  QK8 = (unsigned char*)(wsb + 8*WSZ*2);       // 25.2 MB
  unsigned char*  V8  = QK8 + 4*MDB;                           // 15.7 MB
  unsigned short* Ob  = (unsigned short*)(V8 + V8SZ);          // 25.2 MB

  cvt_w_kernel<<<dim3(144,8),256,0,stream>>>(
      (const float*)d_in[1],(const float*)d_in[2],(const float*)d_in[3],(const float*)d_in[4],
      (const float*)d_in[5],(const float*)d_in[6],(const float*)d_in[7],(const float*)d_in[8], Wb);

  proj_kernel<<<dim3(512,2),256,0,stream>>>(x, Wb, QK8, V8);
  attn_kernel<<<dim3(32,8,2),512,0,stream>>>(QK8, V8, Ob);
  final_kernel<<<dim3(512,2),256,0,stream>>>(x, Ob, Ob + MDB,
                                             Wb+3*WSZ, Wb+7*WSZ, (float*)d_out);
}

// Round 28
// 298.809 us; speedup vs baseline: 1.0946x; 1.0371x over previous
//
#include <hip/hip_runtime.h>
#include <stdint.h>

#define B_ 8
#define S_ 4096
#define D_ 192
#define M_ (B_*S_)
#define VTILE 7680   // V fp8 tile image: 192 rows x (32 s + 8 pad) bytes
#define KTILE 6400   // K fp8 tile image: 32 rows x (192 + 8 pad) bytes

typedef short v8s __attribute__((ext_vector_type(8)));
typedef float v4f __attribute__((ext_vector_type(4)));
typedef unsigned long long ull;

static __device__ __forceinline__ unsigned short f2bf(float f){
  union{float f; unsigned u;} v; v.f=f;
  unsigned u = v.u;
  unsigned r = (u + 0x7fffu + ((u>>16)&1u))>>16;
  return (unsigned short)r;
}
static __device__ __forceinline__ float fexp2(float x){
  return __builtin_amdgcn_exp2f(x);
}

// ---- fp8 e4m3fn pack ----
static __device__ __forceinline__ unsigned sw_fp8(float x){
  union{float f; unsigned u;} v; v.f = x;
  unsigned s = (v.u >> 24) & 0x80u;
  float a = fabsf(x);
  if (a < 0.001953125f) return s;
  if (a >= 240.f) return s | 0x7Eu;
  if (a < 0.015625f) {
    int m = (int)(a*512.f + 0.5f); if(m>7) m=7;
    return s | (unsigned)m;
  }
  int e = (int)((v.u >> 23) & 0xff) - 127;
  unsigned mant = (v.u >> 20) & 0x7u;
  unsigned rest = v.u & 0xFFFFFu;
  if (rest > 0x80000u || (rest == 0x80000u && (mant&1u))) mant++;
  unsigned ee = (unsigned)(e + 7);
  if (mant == 8u){ mant = 0u; ee++; }
  return s | (ee<<3) | mant;
}
template<bool HI>
static __device__ __forceinline__ unsigned pk8(float a, float b, unsigned old){
#if __has_builtin(__builtin_amdgcn_cvt_pk_fp8_f32)
  return __builtin_amdgcn_cvt_pk_fp8_f32(a, b, old, HI);
#else
  unsigned p = sw_fp8(a) | (sw_fp8(b)<<8);
  return HI ? ((old & 0x0000FFFFu) | (p<<16)) : ((old & 0xFFFF0000u) | p);
#endif
}

typedef const __attribute__((address_space(1))) unsigned int gu32;
typedef __attribute__((address_space(3))) unsigned int lu32;
#define GLL16(gp, lp) __builtin_amdgcn_global_load_lds((gu32*)(gp), (lu32*)(lp), 16, 0, 0)

// ---------------- weight conversion fp32 -> bf16 ----------------
__global__ void cvt_w_kernel(const float* w0,const float* w1,const float* w2,const float* w3,
                             const float* w4,const float* w5,const float* w6,const float* w7,
                             unsigned short* dst){
  int w = blockIdx.y;
  const float* src;
  switch(w){
    case 0: src=w0; break; case 1: src=w1; break; case 2: src=w2; break; case 3: src=w3; break;
    case 4: src=w4; break; case 5: src=w5; break; case 6: src=w6; break; default: src=w7; break;
  }
  int i = blockIdx.x*256 + threadIdx.x;
  float v = src[i];
  if(w==0 || w==4 || w==1 || w==5) v *= 0.32267249f;   // sqrt(log2(e)/sqrt(192))
  dst[(size_t)w*36864 + i] = f2bf(v);
}

// ---------------- fused QKV projection, split by path ----------------
// Q8 fp8 [row][192]; K fp8 tile images [path][b][128][32][200B];
// V fp8 tile images [path][b][128][192][40B]. All attn staging becomes
// linear DMA (no register round-trip, no LDS-layout mismatch).
__global__ __launch_bounds__(256) void proj_kernel(
    const float* __restrict__ x, const unsigned short* __restrict__ Wb,
    unsigned char* __restrict__ Q8g, unsigned char* __restrict__ K8t,
    unsigned char* __restrict__ V8)
{
  __shared__ __align__(16) unsigned char Vstage8[2*VTILE];   // 15.4 KB
  const size_t MDB = (size_t)M_*D_;
  int path = blockIdx.y;
  int tid = threadIdx.x;
  int wid = tid>>6, lane = tid&63;
  int lr = lane&15, lg = lane>>4, kb = lg*8;
  int m0 = blockIdx.x*64 + wid*16;
  int row = m0 + lr;

  v8s a[6];
  #pragma unroll
  for(int c=0;c<6;c++){
    const float* xp = &x[(size_t)row*D_ + c*32 + kb];
    float4 f0 = *(const float4*)xp;
    float4 f1 = *(const float4*)(xp+4);
    v8s t;
    t[0]=(short)f2bf(f0.x); t[1]=(short)f2bf(f0.y); t[2]=(short)f2bf(f0.z); t[3]=(short)f2bf(f0.w);
    t[4]=(short)f2bf(f1.x); t[5]=(short)f2bf(f1.y); t[6]=(short)f2bf(f1.z); t[7]=(short)f2bf(f1.w);
    a[c]=t;
  }
  int bidx = m0 / S_;
  int sb   = (blockIdx.x*64) % S_;       // block s-base (64 s = 2 KV tiles)
  int sloc = wid*16 + lg*4;              // local s (0..63)

  // ---- Q: fp8 linear [row][192] ----
  {
    const unsigned short* W = Wb + (size_t)(path*4 + 0)*36864;
    unsigned char* dst = Q8g + (size_t)path*MDB;
    #pragma unroll
    for(int nt=0; nt<12; nt++){
      v4f acc = {0.f,0.f,0.f,0.f};
      int n = nt*16 + lr;
      #pragma unroll
      for(int c=0;c<6;c++){
        v8s bfr = *(const v8s*)&W[(size_t)n*D_ + c*32 + kb];
        acc = __builtin_amdgcn_mfma_f32_16x16x32_bf16(a[c], bfr, acc, 0,0,0);
      }
      int col = nt*16 + lr;
      int r0 = m0 + lg*4;
      #pragma unroll
      for(int r=0;r<4;r++){
        unsigned p = pk8<false>(acc[r], 0.f, 0u);
        dst[(size_t)(r0+r)*D_ + col] = (unsigned char)(p & 0xFF);
      }
    }
  }
  // ---- K: fp8 tile images [32][200B] ----
  {
    const unsigned short* W = Wb + (size_t)(path*4 + 1)*36864;
    unsigned char* dstK = K8t + ((size_t)path*B_ + bidx)*128*KTILE;
    #pragma unroll
    for(int nt=0; nt<12; nt++){
      v4f acc = {0.f,0.f,0.f,0.f};
      int n = nt*16 + lr;
      #pragma unroll
      for(int c=0;c<6;c++){
        v8s bfr = *(const v8s*)&W[(size_t)n*D_ + c*32 + kb];
        acc = __builtin_amdgcn_mfma_f32_16x16x32_bf16(a[c], bfr, acc, 0,0,0);
      }
      int col = nt*16 + lr;
      #pragma unroll
      for(int r=0;r<4;r++){
        int rowS = sb + sloc + r;             // s index within batch
        unsigned p = pk8<false>(acc[r], 0.f, 0u);
        dstK[(size_t)(rowS>>5)*KTILE + (rowS&31)*200 + col] = (unsigned char)(p & 0xFF);
      }
    }
  }
  // ---- V: fp8 tile images [192][40B] via LDS stage ----
  {
    const unsigned short* W = Wb + (size_t)(path*4 + 2)*36864;
    int t2 = sloc >> 5, s32 = sloc & 31;
    #pragma unroll
    for(int nt=0; nt<12; nt++){
      v4f acc = {0.f,0.f,0.f,0.f};
      int n = nt*16 + lr;
      #pragma unroll
      for(int c=0;c<6;c++){
        v8s bfr = *(const v8s*)&W[(size_t)n*D_ + c*32 + kb];
        acc = __builtin_amdgcn_mfma_f32_16x16x32_bf16(a[c], bfr, acc, 0,0,0);
      }
      int col = nt*16 + lr;
      unsigned pk4 = pk8<false>(acc[0], acc[1], 0u);
      pk4 = pk8<true>(acc[2], acc[3], pk4);
      *(unsigned*)&Vstage8[t2*VTILE + col*40 + s32] = pk4;
    }
    __syncthreads();
    unsigned char* dstV = V8 + (size_t)path*((size_t)B_*128*VTILE)
                        + ((size_t)bidx*128 + (sb>>5))*VTILE;
    #pragma unroll
    for(int j=0;j<4;j++){
      int i = tid + j*256;                 // 960 chunks of 16B
      if(i<960) *(v8s*)&dstV[i*16] = *(const v8s*)&Vstage8[i*16];
    }
  }
}

// ---------------- flash attention: fp8 QK + fp8 PV, all-DMA staging ---------
// grid (32,8,2) XCD-remapped, 512 thr (8w x 16q). Full-K, 128 tiles.
// K LDS [32][200B] (16-bank spread), V LDS [192][40B] (2-way free); both
// DMA'd linearly from tile images. Softmax: direct fp8 pk8 + 2 permlane
// (derivation: after swap32(B,A),swap16(B,A): A=k0..3 word, B=k4..7 word).
#define KSTR8 200

__global__ __launch_bounds__(512,4) void attn_kernel(
    const unsigned char* __restrict__ Q8g,
    const unsigned char* __restrict__ K8t,
    const unsigned char* __restrict__ V8,
    unsigned short* __restrict__ Ob)
{
  __shared__ __align__(16) unsigned char KL[2][KTILE];      // 12.8 KB
  __shared__ __align__(16) unsigned char VL8[3][VTILE];     // 22.5 KB (35.3 KB)

  int flat = blockIdx.x + 32*blockIdx.y + 256*blockIdx.z;
  int w = (flat&7)*64 + (flat>>3);   // bijective on [0,512)
  int qi = w & 31;
  int b  = (w>>5) & 7;
  int z  = w>>8;

  const size_t MDB = (size_t)M_*D_;
  const unsigned char* Q8 = Q8g + (size_t)z*MDB;
  const unsigned char* Kp = K8t + ((size_t)z*B_ + b)*128*KTILE;
  const unsigned char* Vp = V8 + (size_t)z*((size_t)B_*128*VTILE) + (size_t)b*128*VTILE;
  unsigned short* O = Ob + (size_t)z*MDB;

  int q0 = qi*128;
  int tid = threadIdx.x, wid=tid>>6, lane=tid&63;
  int lr = lane&15, lg = lane>>4;
  size_t bK = (size_t)b*S_*D_;
  int qrow0 = q0 + wid*16;

  bool doK = tid < 400;               // 400 x 16B = K tile image
  bool doV = tid < 480;               // 480 x 16B = V tile image

  long qf8[6];
  {
    const unsigned char* qp = Q8 + bK + (size_t)(qrow0 + lr)*D_;
    #pragma unroll
    for(int c=0;c<6;c++) qf8[c] = *(const long*)(qp + c*32 + lg*8);
  }
  float lsum = 0.f;
  v4f oacc[12];
  #pragma unroll
  for(int e=0;e<12;e++) oacc[e] = (v4f){0.f,0.f,0.f,0.f};

  auto stage = [&](int t, int kbuf, int vbuf){
    if(doK) GLL16(Kp + (size_t)t*KTILE + tid*16, &KL[kbuf][tid*16]);
    if(doV) GLL16(Vp + (size_t)t*VTILE + tid*16, &VL8[vbuf][tid*16]);
  };
  auto do_qk = [&](int kcur, v4f sacc[2]){
    __builtin_amdgcn_s_setprio(1);
    #pragma unroll
    for(int ct=0; ct<2; ct++){
      v4f s = {0.f,0.f,0.f,0.f};
      const unsigned char* rb = &KL[kcur][(ct*16+lr)*KSTR8];
      #pragma unroll
      for(int c=0;c<6;c++){
        long kf8 = *(const long*)(rb + c*32 + lg*8);
        s = __builtin_amdgcn_mfma_f32_16x16x32_fp8_fp8(kf8, qf8[c], s, 0,0,0);
      }
      sacc[ct]=s;
    }
    __builtin_amdgcn_s_setprio(0);
  };
  auto do_softmax = [&](v4f sacc[2], long& pa8){
    float p00=fexp2(sacc[0][0]), p01=fexp2(sacc[0][1]);
    float p02=fexp2(sacc[0][2]), p03=fexp2(sacc[0][3]);
    float p10=fexp2(sacc[1][0]), p11=fexp2(sacc[1][1]);
    float p12=fexp2(sacc[1][2]), p13=fexp2(sacc[1][3]);
    lsum += ((p00+p01)+(p02+p03)) + ((p10+p11)+(p12+p13));
    unsigned A = pk8<false>(p00,p01,0u); A = pk8<true>(p02,p03,A);   // ct0 r0..3
    unsigned Bx= pk8<false>(p10,p11,0u); Bx= pk8<true>(p12,p13,Bx);  // ct1 r0..3
    asm("v_permlane32_swap_b32 %0, %1" : "+v"(Bx), "+v"(A));
    asm("v_permlane16_swap_b32 %0, %1" : "+v"(Bx), "+v"(A));
    pa8 = (long)(((ull)Bx<<32) | (ull)A);   // A = k lg*8+0..3, Bx = +4..7
  };
  auto do_pv = [&](int vcur, long pa8){
    __builtin_amdgcn_s_setprio(1);
    #pragma unroll
    for(int e=0;e<12;e++){
      long vb8 = *(const long*)&VL8[vcur][(e*16+lr)*40 + lg*8];
      oacc[e] = __builtin_amdgcn_mfma_f32_16x16x32_fp8_fp8(pa8, vb8, oacc[e], 0,0,0);
    }
    __builtin_amdgcn_s_setprio(0);
  };

  stage(0, 0, 0);
  asm volatile("s_waitcnt vmcnt(0)" ::: "memory");
  __syncthreads();

  long pa_prev;
  {
    v4f sacc[2];
    do_qk(0, sacc);
    stage(1, 1, 1);
    __builtin_amdgcn_sched_barrier(0);
    do_softmax(sacc, pa_prev);
    asm volatile("s_waitcnt vmcnt(0)" ::: "memory");
    __syncthreads();
  }

  for(int t=1; t<128; t++){
    v4f sacc[2];
    do_qk(t&1, sacc);
    if(t<127) stage(t+1, (t+1)&1, (t+1)%3);
    __builtin_amdgcn_sched_barrier(0);
    do_pv((t-1)%3, pa_prev);
    do_softmax(sacc, pa_prev);
    asm volatile("s_waitcnt vmcnt(0)" ::: "memory");
    __syncthreads();
  }
  do_pv(127%3, pa_prev);

  // epilogue: per-lane sums (q-row = lr) -> row inverses -> O write (bf16)
  float ps = lsum;
  ps += __shfl_xor(ps, 16);
  ps += __shfl_xor(ps, 32);
  float iv = 1.0f/ps;
  float invr[4];
  #pragma unroll
  for(int r=0;r<4;r++) invr[r] = __shfl(iv, lg*4+r, 16);
  size_t orow0 = ((size_t)b*S_ + qrow0 + lg*4)*D_;
  #pragma unroll
  for(int e=0;e<12;e++){
    #pragma unroll
    for(int r=0;r<4;r++){
      O[orow0 + (size_t)r*D_ + e*16 + lr] = f2bf(oacc[e][r]*invr[r]);
    }
  }
}

// ---------------- final: column-half GEMM split (round-24 form) -------------
__global__ __launch_bounds__(256) void final_kernel(
  const float* __restrict__ x,
  const unsigned short* __restrict__ Or,
  const unsigned short* __restrict__ Ow,
  const unsigned short* __restrict__ WoR,
  const unsigned short* __restrict__ WoW,
  float* __restrict__ out)
{
  int halfn = blockIdx.y;
  int tid=threadIdx.x, wid=tid>>6, lane=tid&63;
  int lr=lane&15, lg=lane>>4, kb=lg*8;
  int m0 = blockIdx.x*64 + wid*16;
  int arow = m0 + lr;
  v8s ar[6], aw[6];
  #pragma unroll
  for(int c=0;c<6;c++){
    ar[c] = *(const v8s*)&Or[(size_t)arow*D_ + c*32 + kb];
    aw[c] = *(const v8s*)&Ow[(size_t)arow*D_ + c*32 + kb];
  }
  int bidx = m0 / S_;
  float rf = x[(size_t)bidx*S_*D_ + 156];
  float wf = x[(size_t)bidx*S_*D_ + 157];
  #pragma unroll
  for(int ntl=0; ntl<6; ntl++){
    int nt = halfn*6 + ntl;
    v4f accR={0.f,0.f,0.f,0.f}, accW={0.f,0.f,0.f,0.f};
    int n = nt*16 + lr;
    #pragma unroll
    for(int c=0;c<6;c++){
      v8s br = *(const v8s*)&WoR[(size_t)n*D_ + c*32 + kb];
      accR = __builtin_amdgcn_mfma_f32_16x16x32_bf16(ar[c], br, accR,0,0,0);
      v8s bw = *(const v8s*)&WoW[(size_t)n*D_ + c*32 + kb];
      accW = __builtin_amdgcn_mfma_f32_16x16x32_bf16(aw[c], bw, accW,0,0,0);
    }
    #pragma unroll
    for(int r=0;r<4;r++){
      int row = m0 + lg*4 + r;
      int col = nt*16 + lr;
      float xv = x[(size_t)row*D_ + col];
      float val = xv + rf*(accR[r]-xv) + wf*(accW[r]-xv);
      if(col==156||col==157) val = 0.f;
      else if(col==158) val = rf+wf;
      out[(size_t)row*D_ + col] = val;
    }
  }
}

extern "C" void kernel_launch(void* const* d_in, const int* in_sizes, int n_in,
                              void* d_out, int out_size, void* d_ws, size_t ws_size,
                              hipStream_t stream) {
  const float* x = (const float*)d_in[0];
  char* wsb = (char*)d_ws;
  const size_t WSZ = 36864;
  const size_t MDB = (size_t)M_*D_;
  const size_t K8SZ = (size_t)2*B_*128*KTILE;                  // 13.1 MB
  const size_t V8SZ = (size_t)2*B_*128*VTILE;                  // 15.7 MB
  unsigned short* Wb  = (unsigned short*)wsb;                  // 0.59 MB
  unsigned char*  Q8  = (unsigned char*)(wsb + 8*WSZ*2);       // 12.6 MB
  unsigned char*  K8t = Q8 + 2*MDB;                            // 13.1 MB
  unsigned char*  V8  = K8t + K8SZ;                            // 15.7 MB
  unsigned short* Ob  = (unsigned short*)(V8 + V8SZ);          // 25.2 MB

  cvt_w_kernel<<<dim3(144,8),256,0,stream>>>(
      (const float*)d_in[1],(const float*)d_in[2],(const float*)d_in[3],(const float*)d_in[4],
      (const float*)d_in[5],(const float*)d_in[6],(const float*)d_in[7],(const float*)d_in[8], Wb);

  proj_kernel<<<dim3(512,2),256,0,stream>>>(x, Wb, Q8, K8t, V8);
  attn_kernel<<<dim3(32,8,2),512,0,stream>>>(Q8, K8t, V8, Ob);
  final_kernel<<<dim3(512,2),256,0,stream>>>(x, Ob, Ob + MDB,
                                             Wb+3*WSZ, Wb+7*WSZ, (float*)d_out);
}

// Round 29
// 288.502 us; speedup vs baseline: 1.1337x; 1.0357x over previous
//
#include <hip/hip_runtime.h>
#include <stdint.h>

#define B_ 8
#define S_ 4096
#define D_ 192
#define M_ (B_*S_)
#define VTILE 13824  // V fp8 tile image: 192 rows x (64 s + 8 pad) bytes
#define KTILE 12800  // K fp8 tile image: 64 rows x (192 + 8 pad) bytes
#define NT_ 64       // KV tiles per sequence (S/64)

typedef short v8s __attribute__((ext_vector_type(8)));
typedef float v4f __attribute__((ext_vector_type(4)));
typedef unsigned long long ull;

static __device__ __forceinline__ unsigned short f2bf(float f){
  union{float f; unsigned u;} v; v.f=f;
  unsigned u = v.u;
  unsigned r = (u + 0x7fffu + ((u>>16)&1u))>>16;
  return (unsigned short)r;
}
static __device__ __forceinline__ float fexp2(float x){
  return __builtin_amdgcn_exp2f(x);
}

// ---- fp8 e4m3fn pack ----
static __device__ __forceinline__ unsigned sw_fp8(float x){
  union{float f; unsigned u;} v; v.f = x;
  unsigned s = (v.u >> 24) & 0x80u;
  float a = fabsf(x);
  if (a < 0.001953125f) return s;
  if (a >= 240.f) return s | 0x7Eu;
  if (a < 0.015625f) {
    int m = (int)(a*512.f + 0.5f); if(m>7) m=7;
    return s | (unsigned)m;
  }
  int e = (int)((v.u >> 23) & 0xff) - 127;
  unsigned mant = (v.u >> 20) & 0x7u;
  unsigned rest = v.u & 0xFFFFFu;
  if (rest > 0x80000u || (rest == 0x80000u && (mant&1u))) mant++;
  unsigned ee = (unsigned)(e + 7);
  if (mant == 8u){ mant = 0u; ee++; }
  return s | (ee<<3) | mant;
}
template<bool HI>
static __device__ __forceinline__ unsigned pk8(float a, float b, unsigned old){
#if __has_builtin(__builtin_amdgcn_cvt_pk_fp8_f32)
  return __builtin_amdgcn_cvt_pk_fp8_f32(a, b, old, HI);
#else
  unsigned p = sw_fp8(a) | (sw_fp8(b)<<8);
  return HI ? ((old & 0x0000FFFFu) | (p<<16)) : ((old & 0xFFFF0000u) | p);
#endif
}

typedef const __attribute__((address_space(1))) unsigned int gu32;
typedef __attribute__((address_space(3))) unsigned int lu32;
#define GLL16(gp, lp) __builtin_amdgcn_global_load_lds((gu32*)(gp), (lu32*)(lp), 16, 0, 0)

// ---------------- weight conversion fp32 -> bf16 ----------------
__global__ void cvt_w_kernel(const float* w0,const float* w1,const float* w2,const float* w3,
                             const float* w4,const float* w5,const float* w6,const float* w7,
                             unsigned short* dst){
  int w = blockIdx.y;
  const float* src;
  switch(w){
    case 0: src=w0; break; case 1: src=w1; break; case 2: src=w2; break; case 3: src=w3; break;
    case 4: src=w4; break; case 5: src=w5; break; case 6: src=w6; break; default: src=w7; break;
  }
  int i = blockIdx.x*256 + threadIdx.x;
  float v = src[i];
  if(w==0 || w==4 || w==1 || w==5) v *= 0.32267249f;   // sqrt(log2(e)/sqrt(192))
  dst[(size_t)w*36864 + i] = f2bf(v);
}

// ---------------- fused QKV projection, split by path ----------------
// Q8 fp8 [row][192]; K fp8 tile images [path][b][64][64][200B];
// V fp8 tile images [path][b][64][192][72B]. Block covers exactly one tile.
__global__ __launch_bounds__(256) void proj_kernel(
    const float* __restrict__ x, const unsigned short* __restrict__ Wb,
    unsigned char* __restrict__ Q8g, unsigned char* __restrict__ K8t,
    unsigned char* __restrict__ V8)
{
  __shared__ __align__(16) unsigned char Vstage8[VTILE];   // 13.8 KB
  const size_t MDB = (size_t)M_*D_;
  int path = blockIdx.y;
  int tid = threadIdx.x;
  int wid = tid>>6, lane = tid&63;
  int lr = lane&15, lg = lane>>4, kb = lg*8;
  int m0 = blockIdx.x*64 + wid*16;
  int row = m0 + lr;

  v8s a[6];
  #pragma unroll
  for(int c=0;c<6;c++){
    const float* xp = &x[(size_t)row*D_ + c*32 + kb];
    float4 f0 = *(const float4*)xp;
    float4 f1 = *(const float4*)(xp+4);
    v8s t;
    t[0]=(short)f2bf(f0.x); t[1]=(short)f2bf(f0.y); t[2]=(short)f2bf(f0.z); t[3]=(short)f2bf(f0.w);
    t[4]=(short)f2bf(f1.x); t[5]=(short)f2bf(f1.y); t[6]=(short)f2bf(f1.z); t[7]=(short)f2bf(f1.w);
    a[c]=t;
  }
  int bidx = m0 / S_;
  int sb   = (blockIdx.x*64) % S_;       // block s-base = one 64-row tile
  int tile = sb >> 6;
  int sloc = wid*16 + lg*4;              // local s (0..63)

  // ---- Q: fp8 linear [row][192] ----
  {
    const unsigned short* W = Wb + (size_t)(path*4 + 0)*36864;
    unsigned char* dst = Q8g + (size_t)path*MDB;
    #pragma unroll
    for(int nt=0; nt<12; nt++){
      v4f acc = {0.f,0.f,0.f,0.f};
      int n = nt*16 + lr;
      #pragma unroll
      for(int c=0;c<6;c++){
        v8s bfr = *(const v8s*)&W[(size_t)n*D_ + c*32 + kb];
        acc = __builtin_amdgcn_mfma_f32_16x16x32_bf16(a[c], bfr, acc, 0,0,0);
      }
      int col = nt*16 + lr;
      int r0 = m0 + lg*4;
      #pragma unroll
      for(int r=0;r<4;r++){
        unsigned p = pk8<false>(acc[r], 0.f, 0u);
        dst[(size_t)(r0+r)*D_ + col] = (unsigned char)(p & 0xFF);
      }
    }
  }
  // ---- K: fp8 tile image [64][200B] ----
  {
    const unsigned short* W = Wb + (size_t)(path*4 + 1)*36864;
    unsigned char* dstK = K8t + (((size_t)path*B_ + bidx)*NT_ + tile)*KTILE;
    #pragma unroll
    for(int nt=0; nt<12; nt++){
      v4f acc = {0.f,0.f,0.f,0.f};
      int n = nt*16 + lr;
      #pragma unroll
      for(int c=0;c<6;c++){
        v8s bfr = *(const v8s*)&W[(size_t)n*D_ + c*32 + kb];
        acc = __builtin_amdgcn_mfma_f32_16x16x32_bf16(a[c], bfr, acc, 0,0,0);
      }
      int col = nt*16 + lr;
      #pragma unroll
      for(int r=0;r<4;r++){
        unsigned p = pk8<false>(acc[r], 0.f, 0u);
        dstK[(size_t)(sloc+r)*200 + col] = (unsigned char)(p & 0xFF);
      }
    }
  }
  // ---- V: fp8 tile image [192][72B] via LDS stage ----
  {
    const unsigned short* W = Wb + (size_t)(path*4 + 2)*36864;
    #pragma unroll
    for(int nt=0; nt<12; nt++){
      v4f acc = {0.f,0.f,0.f,0.f};
      int n = nt*16 + lr;
      #pragma unroll
      for(int c=0;c<6;c++){
        v8s bfr = *(const v8s*)&W[(size_t)n*D_ + c*32 + kb];
        acc = __builtin_amdgcn_mfma_f32_16x16x32_bf16(a[c], bfr, acc, 0,0,0);
      }
      int col = nt*16 + lr;
      unsigned pk4 = pk8<false>(acc[0], acc[1], 0u);
      pk4 = pk8<true>(acc[2], acc[3], pk4);
      *(unsigned*)&Vstage8[col*72 + sloc] = pk4;
    }
    __syncthreads();
    unsigned char* dstV = V8 + (((size_t)path*B_ + bidx)*NT_ + tile)*VTILE;
    #pragma unroll
    for(int j=0;j<4;j++){
      int i = tid + j*256;                 // 864 chunks of 16B
      if(i<864) *(v8s*)&dstV[i*16] = *(const v8s*)&Vstage8[i*16];
    }
  }
}

// ---------------- flash attention: fp8, KV tile 64 (half the barriers) ------
// grid (32,8,2) XCD-remapped, 512 thr (8w x 16q). 64 iterations.
// K LDS [64][200B], V LDS [192][72B] (coprime-stride banks, measured-0 family).
// Softmax: direct fp8 pk8 + permlane per kv-half -> 2 pa8 words.
__global__ __launch_bounds__(512,4) void attn_kernel(
    const unsigned char* __restrict__ Q8g,
    const unsigned char* __restrict__ K8t,
    const unsigned char* __restrict__ V8,
    unsigned short* __restrict__ Ob)
{
  __shared__ __align__(16) unsigned char KL[2][KTILE];      // 25.6 KB
  __shared__ __align__(16) unsigned char VL8[3][VTILE];     // 41.5 KB (67 KB)

  int flat = blockIdx.x + 32*blockIdx.y + 256*blockIdx.z;
  int w = (flat&7)*64 + (flat>>3);   // bijective on [0,512)
  int qi = w & 31;
  int b  = (w>>5) & 7;
  int z  = w>>8;

  const size_t MDB = (size_t)M_*D_;
  const unsigned char* Q8 = Q8g + (size_t)z*MDB;
  const unsigned char* Kp = K8t + ((size_t)z*B_ + b)*NT_*KTILE;
  const unsigned char* Vp = V8 + ((size_t)z*B_ + b)*NT_*VTILE;
  unsigned short* O = Ob + (size_t)z*MDB;

  int q0 = qi*128;
  int tid = threadIdx.x, wid=tid>>6, lane=tid&63;
  int lr = lane&15, lg = lane>>4;
  size_t bK = (size_t)b*S_*D_;
  int qrow0 = q0 + wid*16;

  long qf8[6];
  {
    const unsigned char* qp = Q8 + bK + (size_t)(qrow0 + lr)*D_;
    #pragma unroll
    for(int c=0;c<6;c++) qf8[c] = *(const long*)(qp + c*32 + lg*8);
  }
  float lsum = 0.f;
  v4f oacc[12];
  #pragma unroll
  for(int e=0;e<12;e++) oacc[e] = (v4f){0.f,0.f,0.f,0.f};

  bool k2 = tid < 288;    // 800 K chunks = 512 + 288
  bool v2 = tid < 352;    // 864 V chunks = 512 + 352

  auto stage = [&](int t, int kbuf, int vbuf){
    const unsigned char* kg = Kp + (size_t)t*KTILE;
    const unsigned char* vg = Vp + (size_t)t*VTILE;
    GLL16(kg + tid*16, &KL[kbuf][tid*16]);
    if(k2) GLL16(kg + (512+tid)*16, &KL[kbuf][(512+tid)*16]);
    GLL16(vg + tid*16, &VL8[vbuf][tid*16]);
    if(v2) GLL16(vg + (512+tid)*16, &VL8[vbuf][(512+tid)*16]);
  };
  auto do_qk = [&](int kcur, v4f sacc[4]){
    __builtin_amdgcn_s_setprio(1);
    #pragma unroll
    for(int ct=0; ct<4; ct++){
      v4f s = {0.f,0.f,0.f,0.f};
      const unsigned char* rb = &KL[kcur][(ct*16+lr)*200];
      #pragma unroll
      for(int c=0;c<6;c++){
        long kf8 = *(const long*)(rb + c*32 + lg*8);
        s = __builtin_amdgcn_mfma_f32_16x16x32_fp8_fp8(kf8, qf8[c], s, 0,0,0);
      }
      sacc[ct]=s;
    }
    __builtin_amdgcn_s_setprio(0);
  };
  auto do_softmax = [&](v4f sacc[4], long pa8[2]){
    #pragma unroll
    for(int h=0; h<2; h++){
      v4f s0 = sacc[2*h], s1 = sacc[2*h+1];
      float p00=fexp2(s0[0]), p01=fexp2(s0[1]), p02=fexp2(s0[2]), p03=fexp2(s0[3]);
      float p10=fexp2(s1[0]), p11=fexp2(s1[1]), p12=fexp2(s1[2]), p13=fexp2(s1[3]);
      lsum += ((p00+p01)+(p02+p03)) + ((p10+p11)+(p12+p13));
      unsigned A = pk8<false>(p00,p01,0u); A = pk8<true>(p02,p03,A);
      unsigned Bx= pk8<false>(p10,p11,0u); Bx= pk8<true>(p12,p13,Bx);
      asm("v_permlane32_swap_b32 %0, %1" : "+v"(Bx), "+v"(A));
      asm("v_permlane16_swap_b32 %0, %1" : "+v"(Bx), "+v"(A));
      pa8[h] = (long)(((ull)Bx<<32) | (ull)A);
    }
  };
  auto do_pv = [&](int vcur, long pa8[2]){
    __builtin_amdgcn_s_setprio(1);
    #pragma unroll
    for(int e=0;e<12;e++){
      const unsigned char* vr = &VL8[vcur][(e*16+lr)*72 + lg*8];
      long vb0 = *(const long*)(vr);
      long vb1 = *(const long*)(vr + 32);
      oacc[e] = __builtin_amdgcn_mfma_f32_16x16x32_fp8_fp8(pa8[0], vb0, oacc[e], 0,0,0);
      oacc[e] = __builtin_amdgcn_mfma_f32_16x16x32_fp8_fp8(pa8[1], vb1, oacc[e], 0,0,0);
    }
    __builtin_amdgcn_s_setprio(0);
  };

  stage(0, 0, 0);
  asm volatile("s_waitcnt vmcnt(0)" ::: "memory");
  __syncthreads();

  long pa_prev[2];
  {
    v4f sacc[4];
    do_qk(0, sacc);
    stage(1, 1, 1);
    __builtin_amdgcn_sched_barrier(0);
    do_softmax(sacc, pa_prev);
    asm volatile("s_waitcnt vmcnt(0)" ::: "memory");
    __syncthreads();
  }

  for(int t=1; t<NT_; t++){
    v4f sacc[4];
    do_qk(t&1, sacc);
    if(t<NT_-1) stage(t+1, (t+1)&1, (t+1)%3);
    __builtin_amdgcn_sched_barrier(0);
    do_pv((t-1)%3, pa_prev);
    do_softmax(sacc, pa_prev);
    asm volatile("s_waitcnt vmcnt(0)" ::: "memory");
    __syncthreads();
  }
  do_pv((NT_-1)%3, pa_prev);

  // epilogue: per-lane sums (q-row = lr) -> row inverses -> O write (bf16)
  float ps = lsum;
  ps += __shfl_xor(ps, 16);
  ps += __shfl_xor(ps, 32);
  float iv = 1.0f/ps;
  float invr[4];
  #pragma unroll
  for(int r=0;r<4;r++) invr[r] = __shfl(iv, lg*4+r, 16);
  size_t orow0 = ((size_t)b*S_ + qrow0 + lg*4)*D_;
  #pragma unroll
  for(int e=0;e<12;e++){
    #pragma unroll
    for(int r=0;r<4;r++){
      O[orow0 + (size_t)r*D_ + e*16 + lr] = f2bf(oacc[e][r]*invr[r]);
    }
  }
}

// ---------------- final: column-half GEMM split ----------------
__global__ __launch_bounds__(256) void final_kernel(
  const float* __restrict__ x,
  const unsigned short* __restrict__ Or,
  const unsigned short* __restrict__ Ow,
  const unsigned short* __restrict__ WoR,
  const unsigned short* __restrict__ WoW,
  float* __restrict__ out)
{
  int halfn = blockIdx.y;
  int tid=threadIdx.x, wid=tid>>6, lane=tid&63;
  int lr=lane&15, lg=lane>>4, kb=lg*8;
  int m0 = blockIdx.x*64 + wid*16;
  int arow = m0 + lr;
  v8s ar[6], aw[6];
  #pragma unroll
  for(int c=0;c<6;c++){
    ar[c] = *(const v8s*)&Or[(size_t)arow*D_ + c*32 + kb];
    aw[c] = *(const v8s*)&Ow[(size_t)arow*D_ + c*32 + kb];
  }
  int bidx = m0 / S_;
  float rf = x[(size_t)bidx*S_*D_ + 156];
  float wf = x[(size_t)bidx*S_*D_ + 157];
  #pragma unroll
  for(int ntl=0; ntl<6; ntl++){
    int nt = halfn*6 + ntl;
    v4f accR={0.f,0.f,0.f,0.f}, accW={0.f,0.f,0.f,0.f};
    int n = nt*16 + lr;
    #pragma unroll
    for(int c=0;c<6;c++){
      v8s br = *(const v8s*)&WoR[(size_t)n*D_ + c*32 + kb];
      accR = __builtin_amdgcn_mfma_f32_16x16x32_bf16(ar[c], br, accR,0,0,0);
      v8s bw = *(const v8s*)&WoW[(size_t)n*D_ + c*32 + kb];
      accW = __builtin_amdgcn_mfma_f32_16x16x32_bf16(aw[c], bw, accW,0,0,0);
    }
    #pragma unroll
    for(int r=0;r<4;r++){
      int row = m0 + lg*4 + r;
      int col = nt*16 + lr;
      float xv = x[(size_t)row*D_ + col];
      float val = xv + rf*(accR[r]-xv) + wf*(accW[r]-xv);
      if(col==156||col==157) val = 0.f;
      else if(col==158) val = rf+wf;
      out[(size_t)row*D_ + col] = val;
    }
  }
}

extern "C" void kernel_launch(void* const* d_in, const int* in_sizes, int n_in,
                              void* d_out, int out_size, void* d_ws, size_t ws_size,
                              hipStream_t stream) {
  const float* x = (const float*)d_in[0];
  char* wsb = (char*)d_ws;
  const size_t WSZ = 36864;
  const size_t MDB = (size_t)M_*D_;
  const size_t K8SZ = (size_t)2*B_*NT_*KTILE;                  // 13.1 MB
  const size_t V8SZ = (size_t)2*B_*NT_*VTILE;                  // 14.2 MB
  unsigned short* Wb  = (unsigned short*)wsb;                  // 0.59 MB
  unsigned char*  Q8  = (unsigned char*)(wsb + 8*WSZ*2);       // 12.6 MB
  unsigned char*  K8t = Q8 + 2*MDB;                            // 13.1 MB
  unsigned char*  V8  = K8t + K8SZ;                            // 14.2 MB
  unsigned short* Ob  = (unsigned short*)(V8 + V8SZ);          // 25.2 MB

  cvt_w_kernel<<<dim3(144,8),256,0,stream>>>(
      (const float*)d_in[1],(const float*)d_in[2],(const float*)d_in[3],(const float*)d_in[4],
      (const float*)d_in[5],(const float*)d_in[6],(const float*)d_in[7],(const float*)d_in[8], Wb);

  proj_kernel<<<dim3(512,2),256,0,stream>>>(x, Wb, Q8, K8t, V8);
  attn_kernel<<<dim3(32,8,2),512,0,stream>>>(Q8, K8t, V8, Ob);
  final_kernel<<<dim3(512,2),256,0,stream>>>(x, Ob, Ob + MDB,
                                             Wb+3*WSZ, Wb+7*WSZ, (float*)d_out);
}